// Round 5
// baseline (1927.801 us; speedup 1.0000x reference)
//
#include <hip/hip_runtime.h>
#include <hip/hip_bf16.h>
#include <math.h>

// NODE_DIM=3, EMBED=16
#define ND 3
#define EM 16
#define BK 8             // log2(nodes per bucket)
#define BN 256           // nodes per bucket
#define ACCP 17          // padded LDS accumulator stride
#define HNB 2048         // max buckets (N=500000 -> NB=1954)

__device__ __forceinline__ float sp(float x) {
    // jax.nn.softplus = max(x,0) + log1p(exp(-|x|))
    return fmaxf(x, 0.0f) + log1pf(expf(-fabsf(x)));
}

// ---- bucket pipeline -------------------------------------------------------

__global__ __launch_bounds__(1024) void zero_gcur(int* __restrict__ gcur, int NB) {
    int i = blockIdx.x * 1024 + threadIdx.x;
    if (i < NB) gcur[i] = 0;
}

// Histogram of dst-buckets. 4096 edges per WG.
__global__ __launch_bounds__(256) void hist_kernel(
    const int* __restrict__ ei, int* __restrict__ gcur, int E, int NB)
{
    __shared__ int h[HNB];
    int t = threadIdx.x;
    for (int i = t; i < NB; i += 256) h[i] = 0;
    __syncthreads();
    int base = blockIdx.x * 4096;
#pragma unroll
    for (int i = 0; i < 16; i++) {
        int e = base + i * 256 + t;
        if (e < E) atomicAdd(&h[ei[(size_t)E + e] >> BK], 1);
    }
    __syncthreads();
    for (int i = t; i < NB; i += 256) if (h[i]) atomicAdd(&gcur[i], h[i]);
}

// Exclusive scan of bucket counts -> bbase[NB+1]; reset gcur (NB <= 2048).
__global__ __launch_bounds__(1024) void scan_kernel(
    int* __restrict__ gcur, int* __restrict__ bbase, int NB, int E)
{
    __shared__ int sd[1024];
    int t = threadIdx.x;
    int i0 = 2 * t, i1 = 2 * t + 1;
    int v0 = (i0 < NB) ? gcur[i0] : 0;
    int v1 = (i1 < NB) ? gcur[i1] : 0;
    int pv = v0 + v1;
    sd[t] = pv;
    __syncthreads();
    for (int off = 1; off < 1024; off <<= 1) {
        int a = (t >= off) ? sd[t - off] : 0;
        __syncthreads();
        sd[t] += a;
        __syncthreads();
    }
    int base = sd[t] - pv;  // exclusive prefix of this pair
    if (i0 < NB) { bbase[i0] = base;      gcur[i0] = 0; }
    if (i1 < NB) { bbase[i1] = base + v0; gcur[i1] = 0; }
    if (t == 0) bbase[NB] = E;
}

// Multisplit: stage 4096 edges in regs, LDS histogram, one global reservation
// per (wg,bucket), write packed records (src<<BK | dst&(BN-1)) densely.
__global__ __launch_bounds__(256) void pass2_kernel(
    const int* __restrict__ ei, const int* __restrict__ bbase,
    int* __restrict__ gcur, unsigned* __restrict__ rec, int E, int NB)
{
    __shared__ int h[HNB];
    __shared__ int gslot[HNB];
    int t = threadIdx.x;
    for (int i = t; i < NB; i += 256) h[i] = 0;
    __syncthreads();
    int base = blockIdx.x * 4096;
    unsigned rr[16]; int bb[16];
#pragma unroll
    for (int i = 0; i < 16; i++) {
        int e = base + i * 256 + t;
        if (e < E) {
            int s = ei[e];
            int d = ei[(size_t)E + e];
            bb[i] = d >> BK;
            rr[i] = ((unsigned)s << BK) | (unsigned)(d & (BN - 1));
            atomicAdd(&h[bb[i]], 1);
        } else bb[i] = -1;
    }
    __syncthreads();
    for (int i = t; i < NB; i += 256) {
        int c = h[i];
        if (c > 0) gslot[i] = bbase[i] + atomicAdd(&gcur[i], c);
        h[i] = 0;  // reuse as local cursor
    }
    __syncthreads();
#pragma unroll
    for (int i = 0; i < 16; i++) {
        if (bb[i] >= 0) {
            int r = atomicAdd(&h[bb[i]], 1);
            rec[gslot[bb[i]] + r] = rr[i];
        }
    }
}

// Per-bucket weighted degree + count; stores wrec[j] = edge length for reuse.
// dinv = rsqrt(1+sum_w); rcnt = 1/(1+cnt).
__global__ __launch_bounds__(256) void deg_kernel(
    const unsigned* __restrict__ rec, const int* __restrict__ bbase,
    const float* __restrict__ pos, float* __restrict__ wrec,
    float* __restrict__ dinv, float* __restrict__ rcnt, int N)
{
    __shared__ float posL[BN * 3];
    __shared__ float ws[BN];
    __shared__ int cs[BN];
    int t = threadIdx.x;
    int nb0 = blockIdx.x << BK;
    for (int i = t; i < BN; i += 256) {
        int n = nb0 + i;
        float px = 0, py = 0, pz = 0;
        if (n < N) {
            px = pos[3 * (size_t)n + 0];
            py = pos[3 * (size_t)n + 1];
            pz = pos[3 * (size_t)n + 2];
        }
        posL[i * 3 + 0] = px; posL[i * 3 + 1] = py; posL[i * 3 + 2] = pz;
        ws[i] = 0.0f; cs[i] = 0;
    }
    __syncthreads();
    int rb = bbase[blockIdx.x], re = bbase[blockIdx.x + 1];
    for (int j = rb + t; j < re; j += 256) {
        unsigned r = rec[j];
        int s = r >> BK, dl = r & (BN - 1);
        float dx = posL[dl * 3 + 0] - pos[3 * (size_t)s + 0];
        float dy = posL[dl * 3 + 1] - pos[3 * (size_t)s + 1];
        float dz = posL[dl * 3 + 2] - pos[3 * (size_t)s + 2];
        float w = sqrtf(fmaf(dx, dx, fmaf(dy, dy, dz * dz)));
        wrec[j] = w;
        atomicAdd(&ws[dl], w);
        atomicAdd(&cs[dl], 1);
    }
    __syncthreads();
    for (int i = t; i < BN; i += 256) {
        int n = nb0 + i;
        if (n < N) {
            dinv[n] = rsqrtf(1.0f + ws[i]);
            rcnt[n] = 1.0f / (float)(1 + cs[i]);
        }
    }
}

// x0 = sp(pos@Wi+bi); xwA = dinv[n] * (x0 @ W_g1)   (pre-scaled by dinv[src])
__global__ __launch_bounds__(256) void node_init(
    const float* __restrict__ pos,
    const float* __restrict__ W_init, const float* __restrict__ b_init,
    const float* __restrict__ W_g1, const float* __restrict__ dinv,
    float* __restrict__ xw, int N)
{
    __shared__ float sWi[ND * EM];
    __shared__ float sbi[EM];
    __shared__ float sW1[EM * EM];
    int t = threadIdx.x;
    if (t < ND * EM) sWi[t] = W_init[t];
    if (t < EM)      sbi[t] = b_init[t];
    sW1[t] = W_g1[t];
    __syncthreads();

    int n = blockIdx.x * 256 + t;
    if (n >= N) return;

    float p0 = pos[3 * (size_t)n + 0];
    float p1 = pos[3 * (size_t)n + 1];
    float p2 = pos[3 * (size_t)n + 2];

    float x0[EM];
#pragma unroll
    for (int j = 0; j < EM; j++) {
        float h = fmaf(p0, sWi[0 * EM + j],
                  fmaf(p1, sWi[1 * EM + j],
                  fmaf(p2, sWi[2 * EM + j], sbi[j])));
        x0[j] = sp(h);
    }
    float di = dinv[n];
    float o[EM];
#pragma unroll
    for (int k = 0; k < EM; k++) {
        float a = 0.0f;
#pragma unroll
        for (int j = 0; j < EM; j++) a = fmaf(x0[j], sW1[j * EM + k], a);
        o[k] = a * di;
    }
    float4* xo = (float4*)(xw + (size_t)n * EM);
#pragma unroll
    for (int q = 0; q < 4; q++)
        xo[q] = make_float4(o[4*q+0], o[4*q+1], o[4*q+2], o[4*q+3]);
}

// Fused per-bucket conv. 16 lanes per record; LDS float-atomic accumulation.
// xin pre-scaled by dinv[src]; msg = (wrec*dinv[d]) * xin[s][c]. No pos access.
// mode 1: xout = dinv[n] * (sp(mean + bias) @ W)
// mode 2: y = sp(x@Wp1+bp1); out = (y@Wp2+bp2)/sig
__global__ __launch_bounds__(256, 8) void conv_kernel(
    const unsigned* __restrict__ rec, const float* __restrict__ wrec,
    const int* __restrict__ bbase,
    const float* __restrict__ dinv, const float* __restrict__ rcnt,
    const float* __restrict__ xin,
    const float* __restrict__ bias, const float* __restrict__ W,
    const float* __restrict__ W_p1, const float* __restrict__ b_p1,
    const float* __restrict__ W_p2, const float* __restrict__ b_p2,
    const float* __restrict__ sig,
    float* __restrict__ xout, int N, int mode)
{
    __shared__ float acc[BN * ACCP];    // 17.4 KB
    __shared__ float dinvL[BN];         // 1 KB
    __shared__ float sW[EM * EM];       // W (mode1) or W_p1 (mode2)
    __shared__ float sb[EM];
    __shared__ float sbp1[EM];
    __shared__ float sP2[EM * ND];
    __shared__ float sbp2[ND];

    int t = threadIdx.x;
    int nb0 = blockIdx.x << BK;
    if (mode == 1) {
        sW[t] = W[t];
    } else {
        sW[t] = W_p1[t];
        if (t < EM)      sbp1[t] = b_p1[t];
        if (t < EM * ND) sP2[t] = W_p2[t];
        if (t < ND)      sbp2[t] = b_p2[t];
    }
    if (t < EM) sb[t] = bias[t];
    for (int i = t; i < BN; i += 256) {
        int n = nb0 + i;
        dinvL[i] = (n < N) ? dinv[n] : 0.0f;
    }
    for (int i = t; i < BN * ACCP; i += 256) acc[i] = 0.0f;
    __syncthreads();

    int rb = bbase[blockIdx.x], re = bbase[blockIdx.x + 1];
    int sub = t >> 4, c = t & 15;
    int j = rb + sub;
    // unrolled-by-8: 8 independent random xin lines in flight per thread-slot
    for (; j + 112 < re; j += 128) {
        unsigned r[8]; float wv[8];
#pragma unroll
        for (int u = 0; u < 8; u++) { r[u] = rec[j + 16 * u]; wv[u] = wrec[j + 16 * u]; }
        float xv[8];
#pragma unroll
        for (int u = 0; u < 8; u++) xv[u] = xin[((size_t)(r[u] >> BK) << 4) + c];
#pragma unroll
        for (int u = 0; u < 8; u++) {
            int dl = r[u] & (BN - 1);
            atomicAdd(&acc[dl * ACCP + c], wv[u] * dinvL[dl] * xv[u]);
        }
    }
    for (; j < re; j += 16) {
        unsigned r = rec[j];
        float w = wrec[j];
        int s = r >> BK, dl = r & (BN - 1);
        float xv = xin[((size_t)s << 4) + c];
        atomicAdd(&acc[dl * ACCP + c], w * dinvL[dl] * xv);
    }
    __syncthreads();

    int g = t >> 4;
    for (int i = g; i < BN; i += 16) {
        int n = nb0 + i;
        float xv = 0.0f;
        if (n < N) {
            float self = dinvL[i] * xin[((size_t)n << 4) + c];
            xv = sp(fmaf(acc[i * ACCP + c] + self, rcnt[n], sb[c]));
        }
        acc[i * ACCP + c] = xv;   // same-wave 16-lane group: write then read (lockstep)
        if (n < N) {
            if (mode == 1) {
                float o = 0.0f;
#pragma unroll
                for (int jj = 0; jj < EM; jj++)
                    o = fmaf(acc[i * ACCP + jj], sW[jj * EM + c], o);
                xout[((size_t)n << 4) + c] = dinvL[i] * o;
            } else {
                float a = sbp1[c];
#pragma unroll
                for (int jj = 0; jj < EM; jj++)
                    a = fmaf(acc[i * ACCP + jj], sW[jj * EM + c], a);
                float y = sp(a);
                acc[i * ACCP + c] = y;   // lockstep again
                if (c < ND) {
                    float o = sbp2[c];
#pragma unroll
                    for (int jj = 0; jj < EM; jj++)
                        o = fmaf(acc[i * ACCP + jj], sP2[jj * ND + c], o);
                    xout[(size_t)n * ND + c] = o / sig[n];
                }
            }
        }
    }
}

extern "C" void kernel_launch(void* const* d_in, const int* in_sizes, int n_in,
                              void* d_out, int out_size, void* d_ws, size_t ws_size,
                              hipStream_t stream) {
    const float* pos    = (const float*)d_in[0];
    const float* sig    = (const float*)d_in[1];
    const int*   ei     = (const int*)d_in[2];
    const float* W_init = (const float*)d_in[4];
    const float* b_init = (const float*)d_in[5];
    const float* W_g1   = (const float*)d_in[6];
    const float* b_g1   = (const float*)d_in[7];
    const float* W_g2   = (const float*)d_in[8];
    const float* b_g2   = (const float*)d_in[9];
    const float* W_p1   = (const float*)d_in[10];
    const float* b_p1   = (const float*)d_in[11];
    const float* W_p2   = (const float*)d_in[12];
    const float* b_p2   = (const float*)d_in[13];
    float* out = (float*)d_out;

    int N = in_sizes[0] / ND;
    int E = in_sizes[2] / 2;
    int NB = (N + BN - 1) >> BK;          // 1954 for N=500000
    size_t Ns = (size_t)N, Es = (size_t)E;

    // ws layout (4B units):
    // rec[E] | wrec[E] | bbase[NB+1] | gcur[NB] | dinv[N] | rcnt[N] | xwA[16N] | xwB[16N]
    unsigned* rec = (unsigned*)d_ws;
    float* wrec = (float*)(rec + Es);
    int* bbase = (int*)(wrec + Es);
    int* gcur  = bbase + (NB + 1);
    float* dinv = (float*)(gcur + NB);
    float* rcnt = dinv + Ns;
    float* xwA  = rcnt + Ns;
    float* xwB  = xwA + Ns * EM;

    int nbN = (N + 255) / 256;
    int nbE4 = (E + 4095) / 4096;

    zero_gcur<<<(NB + 1023) / 1024, 1024, 0, stream>>>(gcur, NB);
    hist_kernel<<<nbE4, 256, 0, stream>>>(ei, gcur, E, NB);
    scan_kernel<<<1, 1024, 0, stream>>>(gcur, bbase, NB, E);
    pass2_kernel<<<nbE4, 256, 0, stream>>>(ei, bbase, gcur, rec, E, NB);
    deg_kernel<<<NB, 256, 0, stream>>>(rec, bbase, pos, wrec, dinv, rcnt, N);
    node_init<<<nbN, 256, 0, stream>>>(pos, W_init, b_init, W_g1, dinv, xwA, N);
    conv_kernel<<<NB, 256, 0, stream>>>(rec, wrec, bbase, dinv, rcnt, xwA, b_g1, W_g2,
                                        W_p1, b_p1, W_p2, b_p2, sig, xwB, N, 1);
    conv_kernel<<<NB, 256, 0, stream>>>(rec, wrec, bbase, dinv, rcnt, xwB, b_g2, W_g2,
                                        W_p1, b_p1, W_p2, b_p2, sig, out, N, 2);
}